// Round 9
// baseline (671.613 us; speedup 1.0000x reference)
//
#include <hip/hip_runtime.h>

#define NN 8192
#define HID 256
#define OUT_DIM 64
#define MAX_NNZ 512  // per-row capacity; row nnz ~ Binom(8192,0.03): mean 246, sigma 15.4 -> 17-sigma margin
#define NSEG 32      // NN / 256 cols per wave-segment

typedef float f32x4 __attribute__((ext_vector_type(4)));
typedef unsigned long long u64;

static __device__ __forceinline__ f32x4 nt_load4(const float* p) {
    return __builtin_nontemporal_load(reinterpret_cast<const f32x4*>(p));
}

// ---------------------------------------------------------------------------
// Tiled f32 GEMM (unchanged this round; will show in top-5 once spmm drops)
// ---------------------------------------------------------------------------
template <bool RELU_BIAS>
__global__ __launch_bounds__(256) void gemm_f32(const float* __restrict__ A,
                                                const float* __restrict__ W,
                                                const float* __restrict__ bias,
                                                float* __restrict__ C,
                                                int M, int N, int K) {
    __shared__ float As[16][68];
    __shared__ float Bs[16][68];

    const int tid = threadIdx.x;
    const int tx = tid & 15;
    const int ty = tid >> 4;
    const int brow = blockIdx.x * 64;
    const int bcol = blockIdx.y * 64;

    float acc[4][4] = {};

    for (int k0 = 0; k0 < K; k0 += 16) {
        {
            const int r = tid >> 2;
            const int c4 = (tid & 3) * 4;
            float4 av = *reinterpret_cast<const float4*>(
                &A[(size_t)(brow + r) * K + k0 + c4]);
            As[c4 + 0][r] = av.x;
            As[c4 + 1][r] = av.y;
            As[c4 + 2][r] = av.z;
            As[c4 + 3][r] = av.w;
        }
        {
            const int kk = tid >> 4;
            const int cc = (tid & 15) * 4;
            float4 bv = *reinterpret_cast<const float4*>(
                &W[(size_t)(k0 + kk) * N + bcol + cc]);
            *reinterpret_cast<float4*>(&Bs[kk][cc]) = bv;
        }
        __syncthreads();

#pragma unroll
        for (int kk = 0; kk < 16; ++kk) {
            float4 a4 = *reinterpret_cast<const float4*>(&As[kk][ty * 4]);
            float4 b4 = *reinterpret_cast<const float4*>(&Bs[kk][tx * 4]);
            const float a[4] = {a4.x, a4.y, a4.z, a4.w};
            const float b[4] = {b4.x, b4.y, b4.z, b4.w};
#pragma unroll
            for (int i = 0; i < 4; ++i)
#pragma unroll
                for (int j = 0; j < 4; ++j) acc[i][j] = fmaf(a[i], b[j], acc[i][j]);
        }
        __syncthreads();
    }

#pragma unroll
    for (int i = 0; i < 4; ++i) {
        const int row = brow + ty * 4 + i;
        const int col = bcol + tx * 4;
        float4 v;
        float r[4];
#pragma unroll
        for (int j = 0; j < 4; ++j) {
            float x = acc[i][j];
            if (RELU_BIAS) x = fmaxf(x + bias[col + j], 0.f);
            r[j] = x;
        }
        v.x = r[0]; v.y = r[1]; v.z = r[2]; v.w = r[3];
        *reinterpret_cast<float4*>(&C[(size_t)row * N + col]) = v;
    }
}

// ---------------------------------------------------------------------------
// Fused SpMM v2: per-seg INTERLEAVED stream/compact/gather (wave-per-row).
// v1 post-mortem (209us): phases were globally synchronized, so HBM stream
// (86us/CU), L2 gathers (59us/CU), LDS reads (39us) and writes (20us) ran
// SERIALLY. v2 interleaves per 256-col segment so all units run concurrently.
//  - (idx,w) packed in one u64 -> 1 ds_read_b128 per entry PAIR (was 4x b32)
//  - gathers issued BEFORE next prefetch: consuming them (vmcnt is FIFO,
//    waits drain oldest first) never drains the HBM prefetch
//  - prefetch distance 2 segments
// ---------------------------------------------------------------------------
__global__ __launch_bounds__(256) void spmm_fused(const float* __restrict__ adj,
                                                  const float* __restrict__ sim,
                                                  const float* __restrict__ g,
                                                  const float* __restrict__ b_gcn,
                                                  const float* __restrict__ W_dt,
                                                  const float* __restrict__ b_dt,
                                                  float* __restrict__ out) {
    __shared__ u64 s_pk[4][MAX_NNZ];
    __shared__ float s_feat[4][HID];

    const int tid = threadIdx.x;
    const int wave = tid >> 6;
    const int lane = tid & 63;
    const int row = blockIdx.x * 4 + wave;
    const size_t rowbase = (size_t)row * NN;
    const unsigned long long lt_mask = (1ull << lane) - 1ull;
    const float* gl = g + lane * 4;  // lane's 16B slice of each 1KB g-row

    float4 acc = {0.f, 0.f, 0.f, 0.f};
    int base = 0;  // entries compacted (wave-uniform)
    int done = 0;  // entries gathered

    // Prologue: prefetch segments 0 and 1.
    f32x4 aA = nt_load4(&adj[rowbase + lane * 4]);
    f32x4 sA = nt_load4(&sim[rowbase + lane * 4]);
    f32x4 aB = nt_load4(&adj[rowbase + 256 + lane * 4]);
    f32x4 sB = nt_load4(&sim[rowbase + 256 + lane * 4]);

    for (int seg = 0; seg < NSEG; ++seg) {
        const f32x4 a4 = aA, s4 = sA;
        aA = aB; sA = sB;
        const int col = seg * 256 + lane * 4;

        // ---- compact this segment's nonzeros (ballot-prefix, packed u64) --
        const float av[4] = {a4.x, a4.y, a4.z, a4.w};
        const float sv[4] = {s4.x, s4.y, s4.z, s4.w};
#pragma unroll
        for (int e = 0; e < 4; ++e) {
            const bool hit = (av[e] > 0.f) && (sv[e] > 0.f);
            const unsigned long long m = __ballot(hit);
            if (hit) {
                const int off = base + __popcll(m & lt_mask);
                if (off < MAX_NNZ) {
                    const float w = av[e] * sv[e];
                    s_pk[wave][off] =
                        ((u64)(unsigned)(col + e) << 32) | (u64)__float_as_uint(w);
                }
            }
            base += __popcll(m);
        }
        // Fence ds_write -> ds_read within the wave (no code emitted).
        __builtin_amdgcn_wave_barrier();

        // ---- gather available entry pairs (issued BEFORE next prefetch) ---
        const int avail = (base < MAX_NNZ) ? base : MAX_NNZ;
        for (; done + 2 <= avail; done += 2) {
            const ulonglong2 pk2 =
                *reinterpret_cast<const ulonglong2*>(&s_pk[wave][done]);
            const int j0 = (int)(pk2.x >> 32);
            const int j1 = (int)(pk2.y >> 32);
            const float w0 = __uint_as_float((unsigned)pk2.x);
            const float w1 = __uint_as_float((unsigned)pk2.y);
            const float4 g0 = *reinterpret_cast<const float4*>(gl + (size_t)j0 * HID);
            const float4 g1 = *reinterpret_cast<const float4*>(gl + (size_t)j1 * HID);
            acc.x = fmaf(w0, g0.x, fmaf(w1, g1.x, acc.x));
            acc.y = fmaf(w0, g0.y, fmaf(w1, g1.y, acc.y));
            acc.z = fmaf(w0, g0.z, fmaf(w1, g1.z, acc.z));
            acc.w = fmaf(w0, g0.w, fmaf(w1, g1.w, acc.w));
        }

        // ---- prefetch seg+2 LAST (newest in vmem FIFO) --------------------
        if (seg + 2 < NSEG) {
            const size_t p = rowbase + (size_t)(seg + 2) * 256 + lane * 4;
            aB = nt_load4(&adj[p]);
            sB = nt_load4(&sim[p]);
        }
    }

    // ---- drain tail (0 or 1 entry typically) ------------------------------
    {
        const int avail = (base < MAX_NNZ) ? base : MAX_NNZ;
        for (; done < avail; ++done) {
            const u64 pk = s_pk[wave][done];
            const int j = (int)(pk >> 32);
            const float w = __uint_as_float((unsigned)pk);
            const float4 gv = *reinterpret_cast<const float4*>(gl + (size_t)j * HID);
            acc.x = fmaf(w, gv.x, acc.x);
            acc.y = fmaf(w, gv.y, acc.y);
            acc.z = fmaf(w, gv.z, acc.z);
            acc.w = fmaf(w, gv.w, acc.w);
        }
    }

    // ---- epilogue: feat = relu(acc + b_gcn); out = relu(feat @ W_dt + b_dt)
    const float4 bg = *reinterpret_cast<const float4*>(&b_gcn[lane * 4]);
    float4 feat;
    feat.x = fmaxf(acc.x + bg.x, 0.f);
    feat.y = fmaxf(acc.y + bg.y, 0.f);
    feat.z = fmaxf(acc.z + bg.z, 0.f);
    feat.w = fmaxf(acc.w + bg.w, 0.f);
    *reinterpret_cast<float4*>(&s_feat[wave][lane * 4]) = feat;
    __builtin_amdgcn_wave_barrier();

    float p = 0.f;
#pragma unroll 8
    for (int h4 = 0; h4 < HID / 4; ++h4) {
        const float4 f4 = *reinterpret_cast<const float4*>(&s_feat[wave][h4 * 4]);
        p = fmaf(f4.x, W_dt[(h4 * 4 + 0) * OUT_DIM + lane], p);
        p = fmaf(f4.y, W_dt[(h4 * 4 + 1) * OUT_DIM + lane], p);
        p = fmaf(f4.z, W_dt[(h4 * 4 + 2) * OUT_DIM + lane], p);
        p = fmaf(f4.w, W_dt[(h4 * 4 + 3) * OUT_DIM + lane], p);
    }
    out[(size_t)row * OUT_DIM + lane] = fmaxf(p + b_dt[lane], 0.f);
}

extern "C" void kernel_launch(void* const* d_in, const int* in_sizes, int n_in,
                              void* d_out, int out_size, void* d_ws, size_t ws_size,
                              hipStream_t stream) {
    const float* h      = (const float*)d_in[0];
    const float* adj    = (const float*)d_in[1];
    const float* simlar = (const float*)d_in[2];
    const float* W_proj = (const float*)d_in[3];
    const float* b_proj = (const float*)d_in[4];
    const float* W_gcn  = (const float*)d_in[5];
    const float* b_gcn  = (const float*)d_in[6];
    const float* W_dt   = (const float*)d_in[7];
    const float* b_dt   = (const float*)d_in[8];
    float* out = (float*)d_out;

    (void)ws_size;  // hp (8 MB) + g (8 MB)
    float* hp = (float*)d_ws;
    float* g  = (float*)d_ws + (size_t)NN * HID;

    dim3 gemm_grid(NN / 64, HID / 64);  // (128, 4)
    gemm_f32<true><<<gemm_grid, 256, 0, stream>>>(h, W_proj, b_proj, hp, NN, HID, HID);
    gemm_f32<false><<<gemm_grid, 256, 0, stream>>>(hp, W_gcn, nullptr, g, NN, HID, HID);
    spmm_fused<<<NN / 4, 256, 0, stream>>>(adj, simlar, g, b_gcn, W_dt, b_dt, out);
}

// Round 13
// 617.904 us; speedup vs baseline: 1.0869x; 1.0869x over previous
//
#include <hip/hip_runtime.h>

#define NN 8192
#define HID 256
#define OUT_DIM 64
#define MAX_NNZ 512  // per-row capacity; row nnz ~ Binom(8192,0.03): mean 246, sigma 15.4 -> 17-sigma margin

typedef float f32x4 __attribute__((ext_vector_type(4)));
typedef unsigned long long u64;

static __device__ __forceinline__ f32x4 nt_load4(const float* p) {
    return __builtin_nontemporal_load(reinterpret_cast<const f32x4*>(p));
}

// round-to-nearest-even f32 -> bf16 (no NaN handling needed for this data)
static __device__ __forceinline__ unsigned short f2bf(float x) {
    unsigned u = __float_as_uint(x);
    return (unsigned short)((u + 0x7fffu + ((u >> 16) & 1u)) >> 16);
}
static __device__ __forceinline__ float bf2f(unsigned short s) {
    return __uint_as_float((unsigned)s << 16);
}

// ---------------------------------------------------------------------------
// Tiled f32 GEMM v2: 64x64 tile, BK=16, 256 thr, 4x4 microtile.
// v1 was ~215us (5 TF): suspect full kk-unroll hoisted 32 b128 LDS loads
// (register blowup/spill) + zero global-load/compute overlap.
// v2: register prefetch of next k-tile across the barrier + unroll cap 4.
// OUT_BF16 stores bf16 (for the spmm's gather operand g).
// ---------------------------------------------------------------------------
template <bool RELU_BIAS, bool OUT_BF16>
__global__ __launch_bounds__(256) void gemm_f32(const float* __restrict__ A,
                                                const float* __restrict__ W,
                                                const float* __restrict__ bias,
                                                float* __restrict__ Cf,
                                                unsigned short* __restrict__ Cb,
                                                int M, int N, int K) {
    __shared__ float As[16][68];  // [k][m], +4 pad
    __shared__ float Bs[16][68];  // [k][n], +4 pad

    const int tid = threadIdx.x;
    const int tx = tid & 15;
    const int ty = tid >> 4;
    const int brow = blockIdx.x * 64;
    const int bcol = blockIdx.y * 64;
    const int ar = tid >> 2, ac4 = (tid & 3) * 4;   // A-tile: row, col4
    const int bk = tid >> 4, bc = (tid & 15) * 4;   // B-tile: krow, col4

    // prefetch k-tile 0 into registers
    float4 aReg = *reinterpret_cast<const float4*>(&A[(size_t)(brow + ar) * K + ac4]);
    float4 bReg = *reinterpret_cast<const float4*>(&W[(size_t)bk * N + bcol + bc]);

    float acc[4][4] = {};

    for (int k0 = 0; k0 < K; k0 += 16) {
        As[ac4 + 0][ar] = aReg.x;
        As[ac4 + 1][ar] = aReg.y;
        As[ac4 + 2][ar] = aReg.z;
        As[ac4 + 3][ar] = aReg.w;
        *reinterpret_cast<float4*>(&Bs[bk][bc]) = bReg;
        __syncthreads();

        // prefetch NEXT k-tile while computing this one (hides HBM latency)
        if (k0 + 16 < K) {
            aReg = *reinterpret_cast<const float4*>(
                &A[(size_t)(brow + ar) * K + (k0 + 16) + ac4]);
            bReg = *reinterpret_cast<const float4*>(
                &W[(size_t)(k0 + 16 + bk) * N + bcol + bc]);
        }

#pragma unroll 4
        for (int kk = 0; kk < 16; ++kk) {
            float4 a4 = *reinterpret_cast<const float4*>(&As[kk][ty * 4]);
            float4 b4 = *reinterpret_cast<const float4*>(&Bs[kk][tx * 4]);
            const float a[4] = {a4.x, a4.y, a4.z, a4.w};
            const float b[4] = {b4.x, b4.y, b4.z, b4.w};
#pragma unroll
            for (int i = 0; i < 4; ++i)
#pragma unroll
                for (int j = 0; j < 4; ++j) acc[i][j] = fmaf(a[i], b[j], acc[i][j]);
        }
        __syncthreads();
    }

#pragma unroll
    for (int i = 0; i < 4; ++i) {
        const int row = brow + ty * 4 + i;
        const int col = bcol + tx * 4;
        float r[4];
#pragma unroll
        for (int j = 0; j < 4; ++j) {
            float x = acc[i][j];
            if (RELU_BIAS) x = fmaxf(x + bias[col + j], 0.f);
            r[j] = x;
        }
        if (OUT_BF16) {
            ushort4 st;
            st.x = f2bf(r[0]); st.y = f2bf(r[1]);
            st.z = f2bf(r[2]); st.w = f2bf(r[3]);
            *reinterpret_cast<ushort4*>(&Cb[(size_t)row * N + col]) = st;
        } else {
            float4 v; v.x = r[0]; v.y = r[1]; v.z = r[2]; v.w = r[3];
            *reinterpret_cast<float4*>(&Cf[(size_t)row * N + col]) = v;
        }
    }
}

// ---------------------------------------------------------------------------
// Fused SpMM v3: v1's two-phase structure (best measured: phases have full
// MLP; v2's fine interleave lost 18% to vmcnt-FIFO drains). Changes vs v1:
//  - g stored bf16 (4MB -> fits one XCD L2): gather = 8B/lane dwordx2,
//    halves the L1-port time that dominated phase 2 (123us -> ~60us model)
//  - (idx,w) packed u64 in LDS: 1 ds_read_b128 per entry PAIR
// ---------------------------------------------------------------------------
__global__ __launch_bounds__(256) void spmm_fused(const float* __restrict__ adj,
                                                  const float* __restrict__ sim,
                                                  const unsigned short* __restrict__ gb,
                                                  const float* __restrict__ b_gcn,
                                                  const float* __restrict__ W_dt,
                                                  const float* __restrict__ b_dt,
                                                  float* __restrict__ out) {
    __shared__ u64 s_pk[4][MAX_NNZ];
    __shared__ float s_feat[4][HID];

    const int tid = threadIdx.x;
    const int wave = tid >> 6;
    const int lane = tid & 63;
    const int row = blockIdx.x * 4 + wave;
    const size_t rowbase = (size_t)row * NN;
    const unsigned long long lt_mask = (1ull << lane) - 1ull;

    // ---- phase 1: stream adj/sim, ballot-prefix compact (idx,w) -> LDS ----
    int base = 0;
#pragma unroll 2
    for (int seg = 0; seg < NN / 256; ++seg) {
        const int col = seg * 256 + lane * 4;
        f32x4 a4 = nt_load4(&adj[rowbase + col]);
        f32x4 s4 = nt_load4(&sim[rowbase + col]);
        const float av[4] = {a4.x, a4.y, a4.z, a4.w};
        const float sv[4] = {s4.x, s4.y, s4.z, s4.w};
#pragma unroll
        for (int e = 0; e < 4; ++e) {
            const bool hit = (av[e] > 0.f) && (sv[e] > 0.f);
            const unsigned long long m = __ballot(hit);
            if (hit) {
                const int off = base + __popcll(m & lt_mask);
                if (off < MAX_NNZ) {
                    const float w = av[e] * sv[e];
                    s_pk[wave][off] =
                        ((u64)(unsigned)(col + e) << 32) | (u64)__float_as_uint(w);
                }
            }
            base += __popcll(m);
        }
    }
    const int cnt = (base < MAX_NNZ) ? base : MAX_NNZ;
    __builtin_amdgcn_wave_barrier();  // ds_write -> ds_read fence (no code)

    // ---- phase 2: gather bf16 g-rows, x8 unroll for MLP -------------------
    float4 acc = {0.f, 0.f, 0.f, 0.f};
    const unsigned short* gl = gb + lane * 4;  // lane's 8B slice of 512B row
    int l = 0;
    for (; l + 8 <= cnt; l += 8) {
        const ulonglong2 p01 = *reinterpret_cast<const ulonglong2*>(&s_pk[wave][l + 0]);
        const ulonglong2 p23 = *reinterpret_cast<const ulonglong2*>(&s_pk[wave][l + 2]);
        const ulonglong2 p45 = *reinterpret_cast<const ulonglong2*>(&s_pk[wave][l + 4]);
        const ulonglong2 p67 = *reinterpret_cast<const ulonglong2*>(&s_pk[wave][l + 6]);
        const u64 pk[8] = {p01.x, p01.y, p23.x, p23.y, p45.x, p45.y, p67.x, p67.y};
        ushort4 gv[8];
#pragma unroll
        for (int u = 0; u < 8; ++u)
            gv[u] = *reinterpret_cast<const ushort4*>(
                gl + (size_t)(unsigned)(pk[u] >> 32) * HID);
#pragma unroll
        for (int u = 0; u < 8; ++u) {
            const float w = __uint_as_float((unsigned)pk[u]);
            acc.x = fmaf(w, bf2f(gv[u].x), acc.x);
            acc.y = fmaf(w, bf2f(gv[u].y), acc.y);
            acc.z = fmaf(w, bf2f(gv[u].z), acc.z);
            acc.w = fmaf(w, bf2f(gv[u].w), acc.w);
        }
    }
    for (; l < cnt; ++l) {
        const u64 pk = s_pk[wave][l];
        const float w = __uint_as_float((unsigned)pk);
        const ushort4 gv = *reinterpret_cast<const ushort4*>(
            gl + (size_t)(unsigned)(pk >> 32) * HID);
        acc.x = fmaf(w, bf2f(gv.x), acc.x);
        acc.y = fmaf(w, bf2f(gv.y), acc.y);
        acc.z = fmaf(w, bf2f(gv.z), acc.z);
        acc.w = fmaf(w, bf2f(gv.w), acc.w);
    }

    // ---- phase 3: epilogue ------------------------------------------------
    const float4 bg = *reinterpret_cast<const float4*>(&b_gcn[lane * 4]);
    float4 feat;
    feat.x = fmaxf(acc.x + bg.x, 0.f);
    feat.y = fmaxf(acc.y + bg.y, 0.f);
    feat.z = fmaxf(acc.z + bg.z, 0.f);
    feat.w = fmaxf(acc.w + bg.w, 0.f);
    *reinterpret_cast<float4*>(&s_feat[wave][lane * 4]) = feat;
    __builtin_amdgcn_wave_barrier();

    float p = 0.f;
#pragma unroll 8
    for (int h4 = 0; h4 < HID / 4; ++h4) {
        const float4 f4 = *reinterpret_cast<const float4*>(&s_feat[wave][h4 * 4]);
        p = fmaf(f4.x, W_dt[(h4 * 4 + 0) * OUT_DIM + lane], p);
        p = fmaf(f4.y, W_dt[(h4 * 4 + 1) * OUT_DIM + lane], p);
        p = fmaf(f4.z, W_dt[(h4 * 4 + 2) * OUT_DIM + lane], p);
        p = fmaf(f4.w, W_dt[(h4 * 4 + 3) * OUT_DIM + lane], p);
    }
    out[(size_t)row * OUT_DIM + lane] = fmaxf(p + b_dt[lane], 0.f);
}

extern "C" void kernel_launch(void* const* d_in, const int* in_sizes, int n_in,
                              void* d_out, int out_size, void* d_ws, size_t ws_size,
                              hipStream_t stream) {
    const float* h      = (const float*)d_in[0];
    const float* adj    = (const float*)d_in[1];
    const float* simlar = (const float*)d_in[2];
    const float* W_proj = (const float*)d_in[3];
    const float* b_proj = (const float*)d_in[4];
    const float* W_gcn  = (const float*)d_in[5];
    const float* b_gcn  = (const float*)d_in[6];
    const float* W_dt   = (const float*)d_in[7];
    const float* b_dt   = (const float*)d_in[8];
    float* out = (float*)d_out;

    // Workspace: hp f32 (8 MB) then gb bf16 (4 MB).
    (void)ws_size;
    float* hp = (float*)d_ws;
    unsigned short* gb = (unsigned short*)((char*)d_ws + (size_t)NN * HID * 4);

    dim3 gemm_grid(NN / 64, HID / 64);  // (128, 4)
    gemm_f32<true, false><<<gemm_grid, 256, 0, stream>>>(
        h, W_proj, b_proj, hp, nullptr, NN, HID, HID);
    gemm_f32<false, true><<<gemm_grid, 256, 0, stream>>>(
        hp, W_gcn, nullptr, nullptr, gb, NN, HID, HID);
    spmm_fused<<<NN / 4, 256, 0, stream>>>(adj, simlar, gb, b_gcn, W_dt, b_dt, out);
}

// Round 15
// 581.114 us; speedup vs baseline: 1.1557x; 1.0633x over previous
//
#include <hip/hip_runtime.h>

#define NN 8192
#define HID 256
#define OUT_DIM 64
#define MAX_NNZ 512  // row nnz ~ Binom(8192,0.03): mean 246, sigma 15.4 -> 17-sigma margin

typedef float f32x4 __attribute__((ext_vector_type(4)));
typedef _Float16 f16x8 __attribute__((ext_vector_type(8)));
typedef unsigned long long u64;

static __device__ __forceinline__ f32x4 nt_load4(const float* p) {
    return __builtin_nontemporal_load(reinterpret_cast<const f32x4*>(p));
}
static __device__ __forceinline__ float h2f_bits(unsigned short s) {
    _Float16 h;
    __builtin_memcpy(&h, &s, 2);
    return (float)h;
}

// ---------------------------------------------------------------------------
// prep: W[k][n] f32 -> WT[n][k] f16 (transposed so GEMM B-frags are contiguous
// in k -> single ds_read_b128 per fragment). 256KB total, L2-resident.
// ---------------------------------------------------------------------------
__global__ __launch_bounds__(256) void prep_w(const float* __restrict__ Wp,
                                              const float* __restrict__ Wg,
                                              _Float16* __restrict__ WpT,
                                              _Float16* __restrict__ WgT) {
    const int b = blockIdx.x;   // 0..511
    const int t = threadIdx.x;  // k
    const int n = b & 255;
    if (b < 256) WpT[n * HID + t] = (_Float16)Wp[t * HID + n];
    else         WgT[n * HID + t] = (_Float16)Wg[t * HID + n];
}

// ---------------------------------------------------------------------------
// MFMA f16 GEMM, M=8192 K=256 N=256. Block: 256 thr = 4 waves; BM=64 (16/wave),
// BN=64 (4 n-frags/wave); K-loop barrier-free (B staged once in LDS, A from
// global 16B/lane frags). mfma_f32_16x16x32_f16; C/D: col=lane&15,
// row=(lane>>4)*4+reg [m89-verified layout]. LDS [64][264] pad -> 2-way banks.
// GEMM1: A=h f32 (cvt in-kernel), epilogue bias+relu, out f16.
// ---------------------------------------------------------------------------
__global__ __launch_bounds__(256) void gemm1_mfma(const float* __restrict__ A,
                                                  const _Float16* __restrict__ BT,
                                                  const float* __restrict__ bias,
                                                  _Float16* __restrict__ C) {
    __shared__ _Float16 Bs[64][264];

    const int tid = threadIdx.x;
    const int wave = tid >> 6, lane = tid & 63;
    const int brow = blockIdx.x * 64;
    const int bcol = blockIdx.y * 64;

    {   // stage B-slice: 64 cols x 256 k (32KB)
        const int r = tid >> 2;
        const int p = (tid & 3) * 64;
        const f16x8* src = reinterpret_cast<const f16x8*>(&BT[(size_t)(bcol + r) * HID + p]);
#pragma unroll
        for (int i = 0; i < 8; ++i)
            *reinterpret_cast<f16x8*>(&Bs[r][p + i * 8]) = src[i];
    }
    __syncthreads();

    const int m = lane & 15;
    const int kg = lane >> 4;
    const float* arowp = A + (size_t)(brow + wave * 16 + m) * HID;

    f32x4 acc0 = {0.f, 0.f, 0.f, 0.f}, acc1 = acc0, acc2 = acc0, acc3 = acc0;

#pragma unroll 2
    for (int ks = 0; ks < 8; ++ks) {
        const int kb = ks * 32 + kg * 8;
        f32x4 a0 = *reinterpret_cast<const f32x4*>(arowp + kb);
        f32x4 a1 = *reinterpret_cast<const f32x4*>(arowp + kb + 4);
        f16x8 af;
        af[0] = (_Float16)a0[0]; af[1] = (_Float16)a0[1];
        af[2] = (_Float16)a0[2]; af[3] = (_Float16)a0[3];
        af[4] = (_Float16)a1[0]; af[5] = (_Float16)a1[1];
        af[6] = (_Float16)a1[2]; af[7] = (_Float16)a1[3];

        f16x8 b0 = *reinterpret_cast<const f16x8*>(&Bs[ 0 + m][kb]);
        f16x8 b1 = *reinterpret_cast<const f16x8*>(&Bs[16 + m][kb]);
        f16x8 b2 = *reinterpret_cast<const f16x8*>(&Bs[32 + m][kb]);
        f16x8 b3 = *reinterpret_cast<const f16x8*>(&Bs[48 + m][kb]);
        acc0 = __builtin_amdgcn_mfma_f32_16x16x32_f16(af, b0, acc0, 0, 0, 0);
        acc1 = __builtin_amdgcn_mfma_f32_16x16x32_f16(af, b1, acc1, 0, 0, 0);
        acc2 = __builtin_amdgcn_mfma_f32_16x16x32_f16(af, b2, acc2, 0, 0, 0);
        acc3 = __builtin_amdgcn_mfma_f32_16x16x32_f16(af, b3, acc3, 0, 0, 0);
    }

    const int rbase = brow + wave * 16 + kg * 4;
#pragma unroll
    for (int r = 0; r < 4; ++r) {
        const size_t ro = (size_t)(rbase + r) * HID;
        int c0 = bcol + m;
        C[ro + c0]      = (_Float16)fmaxf(acc0[r] + bias[c0], 0.f);
        C[ro + c0 + 16] = (_Float16)fmaxf(acc1[r] + bias[c0 + 16], 0.f);
        C[ro + c0 + 32] = (_Float16)fmaxf(acc2[r] + bias[c0 + 32], 0.f);
        C[ro + c0 + 48] = (_Float16)fmaxf(acc3[r] + bias[c0 + 48], 0.f);
    }
}

// GEMM2: A = hp f16 (direct frag loads), no bias/relu, out g f16.
__global__ __launch_bounds__(256) void gemm2_mfma(const _Float16* __restrict__ A,
                                                  const _Float16* __restrict__ BT,
                                                  _Float16* __restrict__ C) {
    __shared__ _Float16 Bs[64][264];

    const int tid = threadIdx.x;
    const int wave = tid >> 6, lane = tid & 63;
    const int brow = blockIdx.x * 64;
    const int bcol = blockIdx.y * 64;

    {
        const int r = tid >> 2;
        const int p = (tid & 3) * 64;
        const f16x8* src = reinterpret_cast<const f16x8*>(&BT[(size_t)(bcol + r) * HID + p]);
#pragma unroll
        for (int i = 0; i < 8; ++i)
            *reinterpret_cast<f16x8*>(&Bs[r][p + i * 8]) = src[i];
    }
    __syncthreads();

    const int m = lane & 15;
    const int kg = lane >> 4;
    const _Float16* arowp = A + (size_t)(brow + wave * 16 + m) * HID;

    f32x4 acc0 = {0.f, 0.f, 0.f, 0.f}, acc1 = acc0, acc2 = acc0, acc3 = acc0;

#pragma unroll 2
    for (int ks = 0; ks < 8; ++ks) {
        const int kb = ks * 32 + kg * 8;
        f16x8 af = *reinterpret_cast<const f16x8*>(arowp + kb);
        f16x8 b0 = *reinterpret_cast<const f16x8*>(&Bs[ 0 + m][kb]);
        f16x8 b1 = *reinterpret_cast<const f16x8*>(&Bs[16 + m][kb]);
        f16x8 b2 = *reinterpret_cast<const f16x8*>(&Bs[32 + m][kb]);
        f16x8 b3 = *reinterpret_cast<const f16x8*>(&Bs[48 + m][kb]);
        acc0 = __builtin_amdgcn_mfma_f32_16x16x32_f16(af, b0, acc0, 0, 0, 0);
        acc1 = __builtin_amdgcn_mfma_f32_16x16x32_f16(af, b1, acc1, 0, 0, 0);
        acc2 = __builtin_amdgcn_mfma_f32_16x16x32_f16(af, b2, acc2, 0, 0, 0);
        acc3 = __builtin_amdgcn_mfma_f32_16x16x32_f16(af, b3, acc3, 0, 0, 0);
    }

    const int rbase = brow + wave * 16 + kg * 4;
#pragma unroll
    for (int r = 0; r < 4; ++r) {
        const size_t ro = (size_t)(rbase + r) * HID;
        int c0 = bcol + m;
        C[ro + c0]      = (_Float16)acc0[r];
        C[ro + c0 + 16] = (_Float16)acc1[r];
        C[ro + c0 + 32] = (_Float16)acc2[r];
        C[ro + c0 + 48] = (_Float16)acc3[r];
    }
}

// ---------------------------------------------------------------------------
// Fused SpMM (measured 181us r13): two-phase wave-per-row, byte-identical to
// v3 except g is f16 (better precision than bf16 at same bytes).
// ---------------------------------------------------------------------------
__global__ __launch_bounds__(256) void spmm_fused(const float* __restrict__ adj,
                                                  const float* __restrict__ sim,
                                                  const unsigned short* __restrict__ gb,
                                                  const float* __restrict__ b_gcn,
                                                  const float* __restrict__ W_dt,
                                                  const float* __restrict__ b_dt,
                                                  float* __restrict__ out) {
    __shared__ u64 s_pk[4][MAX_NNZ];
    __shared__ float s_feat[4][HID];

    const int tid = threadIdx.x;
    const int wave = tid >> 6;
    const int lane = tid & 63;
    const int row = blockIdx.x * 4 + wave;
    const size_t rowbase = (size_t)row * NN;
    const unsigned long long lt_mask = (1ull << lane) - 1ull;

    int base = 0;
#pragma unroll 2
    for (int seg = 0; seg < NN / 256; ++seg) {
        const int col = seg * 256 + lane * 4;
        f32x4 a4 = nt_load4(&adj[rowbase + col]);
        f32x4 s4 = nt_load4(&sim[rowbase + col]);
        const float av[4] = {a4.x, a4.y, a4.z, a4.w};
        const float sv[4] = {s4.x, s4.y, s4.z, s4.w};
#pragma unroll
        for (int e = 0; e < 4; ++e) {
            const bool hit = (av[e] > 0.f) && (sv[e] > 0.f);
            const unsigned long long mm = __ballot(hit);
            if (hit) {
                const int off = base + __popcll(mm & lt_mask);
                if (off < MAX_NNZ) {
                    const float w = av[e] * sv[e];
                    s_pk[wave][off] =
                        ((u64)(unsigned)(col + e) << 32) | (u64)__float_as_uint(w);
                }
            }
            base += __popcll(mm);
        }
    }
    const int cnt = (base < MAX_NNZ) ? base : MAX_NNZ;
    __builtin_amdgcn_wave_barrier();

    float4 acc = {0.f, 0.f, 0.f, 0.f};
    const unsigned short* gl = gb + lane * 4;
    int l = 0;
    for (; l + 8 <= cnt; l += 8) {
        const ulonglong2 p01 = *reinterpret_cast<const ulonglong2*>(&s_pk[wave][l + 0]);
        const ulonglong2 p23 = *reinterpret_cast<const ulonglong2*>(&s_pk[wave][l + 2]);
        const ulonglong2 p45 = *reinterpret_cast<const ulonglong2*>(&s_pk[wave][l + 4]);
        const ulonglong2 p67 = *reinterpret_cast<const ulonglong2*>(&s_pk[wave][l + 6]);
        const u64 pk[8] = {p01.x, p01.y, p23.x, p23.y, p45.x, p45.y, p67.x, p67.y};
        ushort4 gv[8];
#pragma unroll
        for (int u = 0; u < 8; ++u)
            gv[u] = *reinterpret_cast<const ushort4*>(
                gl + (size_t)(unsigned)(pk[u] >> 32) * HID);
#pragma unroll
        for (int u = 0; u < 8; ++u) {
            const float w = __uint_as_float((unsigned)pk[u]);
            acc.x = fmaf(w, h2f_bits(gv[u].x), acc.x);
            acc.y = fmaf(w, h2f_bits(gv[u].y), acc.y);
            acc.z = fmaf(w, h2f_bits(gv[u].z), acc.z);
            acc.w = fmaf(w, h2f_bits(gv[u].w), acc.w);
        }
    }
    for (; l < cnt; ++l) {
        const u64 pk = s_pk[wave][l];
        const float w = __uint_as_float((unsigned)pk);
        const ushort4 gv = *reinterpret_cast<const ushort4*>(
            gl + (size_t)(unsigned)(pk >> 32) * HID);
        acc.x = fmaf(w, h2f_bits(gv.x), acc.x);
        acc.y = fmaf(w, h2f_bits(gv.y), acc.y);
        acc.z = fmaf(w, h2f_bits(gv.z), acc.z);
        acc.w = fmaf(w, h2f_bits(gv.w), acc.w);
    }

    const float4 bg = *reinterpret_cast<const float4*>(&b_gcn[lane * 4]);
    float4 feat;
    feat.x = fmaxf(acc.x + bg.x, 0.f);
    feat.y = fmaxf(acc.y + bg.y, 0.f);
    feat.z = fmaxf(acc.z + bg.z, 0.f);
    feat.w = fmaxf(acc.w + bg.w, 0.f);
    *reinterpret_cast<float4*>(&s_feat[wave][lane * 4]) = feat;
    __builtin_amdgcn_wave_barrier();

    float p = 0.f;
#pragma unroll 8
    for (int h4 = 0; h4 < HID / 4; ++h4) {
        const float4 f4 = *reinterpret_cast<const float4*>(&s_feat[wave][h4 * 4]);
        p = fmaf(f4.x, W_dt[(h4 * 4 + 0) * OUT_DIM + lane], p);
        p = fmaf(f4.y, W_dt[(h4 * 4 + 1) * OUT_DIM + lane], p);
        p = fmaf(f4.z, W_dt[(h4 * 4 + 2) * OUT_DIM + lane], p);
        p = fmaf(f4.w, W_dt[(h4 * 4 + 3) * OUT_DIM + lane], p);
    }
    out[(size_t)row * OUT_DIM + lane] = fmaxf(p + b_dt[lane], 0.f);
}

extern "C" void kernel_launch(void* const* d_in, const int* in_sizes, int n_in,
                              void* d_out, int out_size, void* d_ws, size_t ws_size,
                              hipStream_t stream) {
    const float* h      = (const float*)d_in[0];
    const float* adj    = (const float*)d_in[1];
    const float* simlar = (const float*)d_in[2];
    const float* W_proj = (const float*)d_in[3];
    const float* b_proj = (const float*)d_in[4];
    const float* W_gcn  = (const float*)d_in[5];
    const float* b_gcn  = (const float*)d_in[6];
    const float* W_dt   = (const float*)d_in[7];
    const float* b_dt   = (const float*)d_in[8];
    float* out = (float*)d_out;

    // ws: hp f16 [0,4M) | g f16 [4M,8M) | WpT,WgT f16 [8M, 8.25M)
    (void)ws_size;
    _Float16* hp  = (_Float16*)d_ws;
    _Float16* gb  = (_Float16*)((char*)d_ws + (4u << 20));
    _Float16* WpT = (_Float16*)((char*)d_ws + (8u << 20));
    _Float16* WgT = WpT + HID * HID;

    prep_w<<<512, 256, 0, stream>>>(W_proj, W_gcn, WpT, WgT);
    gemm1_mfma<<<dim3(128, 4), 256, 0, stream>>>(h, WpT, b_proj, hp);
    gemm2_mfma<<<dim3(128, 4), 256, 0, stream>>>(hp, WgT, gb);
    spmm_fused<<<NN / 4, 256, 0, stream>>>(adj, simlar, (const unsigned short*)gb,
                                           b_gcn, W_dt, b_dt, out);
}